// Round 2
// 462.080 us; speedup vs baseline: 1.0040x; 1.0040x over previous
//
#include <hip/hip_runtime.h>
#include <hip/hip_bf16.h>
#include <stdint.h>

#define N_NODES 32768
#define N_EDGES 262144

typedef __attribute__((ext_vector_type(8))) short short8;
typedef __attribute__((ext_vector_type(4))) float f32x4;
typedef __attribute__((ext_vector_type(4))) uint u32x4;

typedef const __attribute__((address_space(1))) void* gvp;
typedef __attribute__((address_space(3))) void* lvp;

__device__ __forceinline__ float bf2f(ushort u) {
  return __uint_as_float(((uint)u) << 16);
}
__device__ __forceinline__ ushort f2bf(float f) {
  uint x = __float_as_uint(f);
  uint r = (x + 0x7fffu + ((x >> 16) & 1u)) >> 16;
  return (ushort)r;
}
__device__ __forceinline__ float loadf(const void* p, size_t i, int isbf) {
  return isbf ? bf2f(((const ushort*)p)[i]) : ((const float*)p)[i];
}

// ---------------- dtype detection (bf16-packed vs fp32 inputs) ----------------
__global__ void detect_dtype(const uint* __restrict__ xw, int* __restrict__ flag) {
  __shared__ int cnt;
  if (threadIdx.x == 0) cnt = 0;
  __syncthreads();
  int good = 0;
  for (int i = threadIdx.x; i < 1024; i += 256) {
    uint lo = xw[i] & 0xFFFFu;
    uint ef = (lo >> 7) & 0xFFu;
    if (lo == 0u || (ef >= 0x60u && ef <= 0x90u)) good++;
  }
  atomicAdd(&cnt, good);
  __syncthreads();
  if (threadIdx.x == 0) *flag = (cnt >= 614) ? 1 : 0;
}

// ---------------- merged prep: all weights + xp ----------------
// blocks [0,2048): W2T (1024x512)       [2048,2304): WnpT (512x128)
// [2304,2560): Wn_pad (128x512)         [2560,2564): small vectors
// [2564,...): xp (32768x128)
__global__ void prep_all(const void* __restrict__ Wa, const void* __restrict__ Wn,
                         const void* __restrict__ ba, const void* __restrict__ bn,
                         const void* __restrict__ aw, const void* __restrict__ x,
                         const int* __restrict__ flag,
                         ushort* __restrict__ W2T, ushort* __restrict__ WnpT,
                         ushort* __restrict__ Wn_pad, float* __restrict__ bias2,
                         float* __restrict__ bnf, float* __restrict__ wf,
                         float* __restrict__ zbias, ushort* __restrict__ xp) {
  const int fl = *flag;
  const int b = blockIdx.x;
  if (b < 2048) {
    int t = b * 256 + threadIdx.x;           // 1024*512
    int n = t >> 9, k = t & 511;
    size_t idx = (n < 512) ? ((size_t)k * 512 + n) : ((size_t)(512 + k) * 512 + (n - 512));
    W2T[t] = f2bf(loadf(Wa, idx, fl));
  } else if (b < 2304) {
    int t = (b - 2048) * 256 + threadIdx.x;  // 512*128: WnpT[n][k] = Wn[k][n]
    int n = t >> 7, k = t & 127;
    WnpT[t] = (k < 118) ? f2bf(loadf(Wn, (size_t)k * 512 + n, fl)) : (ushort)0;
  } else if (b < 2560) {
    int t = (b - 2304) * 256 + threadIdx.x;  // 128*512: Wn_pad[n][j] = Wn[n][j] (rows padded)
    int n = t >> 9, j = t & 511;
    Wn_pad[t] = (n < 118) ? f2bf(loadf(Wn, (size_t)n * 512 + j, fl)) : (ushort)0;
  } else if (b < 2564) {
    int t = (b - 2560) * 256 + threadIdx.x;  // 1024
    if (t < 1024) bias2[t] = (t < 512) ? loadf(ba, t, fl) : 0.f;
    if (t < 512) { bnf[t] = loadf(bn, t, fl); wf[t] = loadf(aw, t, fl); }
    if (t < 128) zbias[t] = 0.f;
  } else {
    int t = (b - 2564) * 256 + threadIdx.x;  // 32768*128
    int i = t >> 7, k = t & 127;
    xp[t] = (k < 118) ? f2bf(loadf(x, (size_t)i * 118 + k, fl)) : (ushort)0;
  }
}

// bc[j] = sum_k bnf[k] * W2[k][j] + bias2[j]   (W2T is [1024][512])
// one wave per output j
__global__ __launch_bounds__(256)
void build_bc(const ushort* __restrict__ W2T, const float* __restrict__ bnf,
              const float* __restrict__ bias2, float* __restrict__ bc) {
  const int wave = threadIdx.x >> 6, lane = threadIdx.x & 63;
  const int j = blockIdx.x * 4 + wave;   // 256 blocks -> 1024 outputs
  const uint4 v = *(const uint4*)(W2T + (size_t)j * 512 + lane * 8);
  const float4 b0 = *(const float4*)(bnf + lane * 8);
  const float4 b1 = *(const float4*)(bnf + lane * 8 + 4);
  const uint w[4] = {v.x, v.y, v.z, v.w};
  const float bb[8] = {b0.x, b0.y, b0.z, b0.w, b1.x, b1.y, b1.z, b1.w};
  float s = 0.f;
#pragma unroll
  for (int i = 0; i < 4; ++i) {
    s += __uint_as_float(w[i] << 16) * bb[2 * i];
    s += __uint_as_float(w[i] & 0xffff0000u) * bb[2 * i + 1];
  }
  s += __shfl_xor(s, 1);  s += __shfl_xor(s, 2);  s += __shfl_xor(s, 4);
  s += __shfl_xor(s, 8);  s += __shfl_xor(s, 16); s += __shfl_xor(s, 32);
  if (lane == 0) bc[j] = s + bias2[j];
}

// ---------------- CSR build (dst-sorted source-node index) ----------------
__global__ void csr_count(const int* __restrict__ dst, int* __restrict__ cnt) {
  int e = blockIdx.x * blockDim.x + threadIdx.x;
  atomicAdd(&cnt[dst[e]], 1);
}

__global__ __launch_bounds__(1024)
void csr_scan(const int* __restrict__ cnt, int* __restrict__ rowptr,
              int* __restrict__ cursor) {
  __shared__ int part[1024];
  const int t = threadIdx.x;
  const int base = t * 32;
  int loc[32];
  int s = 0;
#pragma unroll
  for (int i = 0; i < 32; ++i) { loc[i] = s; s += cnt[base + i]; }
  part[t] = s;
  __syncthreads();
  for (int off = 1; off < 1024; off <<= 1) {
    int v = (t >= off) ? part[t - off] : 0;
    __syncthreads();
    part[t] += v;
    __syncthreads();
  }
  int pre = (t == 0) ? 0 : part[t - 1];
#pragma unroll
  for (int i = 0; i < 32; ++i) {
    int v = pre + loc[i];
    rowptr[base + i] = v;
    cursor[base + i] = v;
  }
  if (t == 1023) rowptr[N_NODES] = part[1023];
}

// Fold the src[] indirection into the CSR permutation: esrc[p] = src[e].
// node_fused then has a 2-level chain (esrc -> data) instead of 3.
__global__ void csr_fill(const int* __restrict__ dst, const int* __restrict__ src,
                         int* __restrict__ cursor, int* __restrict__ esrc) {
  int e = blockIdx.x * blockDim.x + threadIdx.x;
  int p = atomicAdd(&cursor[dst[e]], 1);
  esrc[p] = src[e];
}

// ---------------- GEMM: C[M,N](bf16) = A[M,K](bf16) @ B + bias; BT = B^T [N,K] ----------------
__global__ __launch_bounds__(256)
void gemm_bf16(const ushort* __restrict__ A, const ushort* __restrict__ BT,
               const float* __restrict__ bias, ushort* __restrict__ C,
               int M, int N, int K) {
  __shared__ __align__(16) ushort As[128 * 32];
  __shared__ __align__(16) ushort Bs[128 * 32];
  const int tid = threadIdx.x, wave = tid >> 6, lane = tid & 63;
  const int bm = blockIdx.y * 128, bn = blockIdx.x * 128;
  const int wm = (wave >> 1) * 64, wn = (wave & 1) * 64;
  const int fcol = lane & 15, quad = lane >> 4;

  const f32x4 zero = {0.f, 0.f, 0.f, 0.f};
  f32x4 acc[4][4];
#pragma unroll
  for (int i = 0; i < 4; ++i)
#pragma unroll
    for (int j = 0; j < 4; ++j) acc[i][j] = zero;

  for (int k0 = 0; k0 < K; k0 += 32) {
#pragma unroll
    for (int r = 0; r < 2; ++r) {
      int o = r * 4096 + wave * 1024 + lane * 16;
      int row = o >> 6;
      int ke = (o & 63) >> 1;
      const ushort* gA = A + (size_t)(bm + row) * K + k0 + ke;
      const ushort* gB = BT + (size_t)(bn + row) * K + k0 + ke;
      ushort* lA = As + ((r * 4096 + wave * 1024) >> 1);
      ushort* lB = Bs + ((r * 4096 + wave * 1024) >> 1);
      __builtin_amdgcn_global_load_lds((gvp)(const void*)gA, (lvp)(void*)lA, 16, 0, 0);
      __builtin_amdgcn_global_load_lds((gvp)(const void*)gB, (lvp)(void*)lB, 16, 0, 0);
    }
    __syncthreads();
    short8 a[4], b[4];
#pragma unroll
    for (int i = 0; i < 4; ++i) {
      a[i] = *(const short8*)&As[(wm + i * 16 + fcol) * 32 + quad * 8];
      b[i] = *(const short8*)&Bs[(wn + i * 16 + fcol) * 32 + quad * 8];
    }
#pragma unroll
    for (int i = 0; i < 4; ++i)
#pragma unroll
      for (int j = 0; j < 4; ++j)
        acc[i][j] = __builtin_amdgcn_mfma_f32_16x16x32_bf16(a[i], b[j], acc[i][j], 0, 0, 0);
    __syncthreads();
  }

#pragma unroll
  for (int i = 0; i < 4; ++i) {
    int rowb = bm + wm + i * 16 + quad * 4;
#pragma unroll
    for (int j = 0; j < 4; ++j) {
      int col = bn + wn + j * 16 + fcol;
      float bb = bias[col];
#pragma unroll
      for (int r = 0; r < 4; ++r) {
        C[(size_t)(rowb + r) * N + col] = f2bf(acc[i][j][r] + bb);
      }
    }
  }
}

// ---------------- fused per-node: score + online-softmax + aggregation ----------------
// Software-pipelined: data loads for edge j+1 are issued before computing edge j,
// so the random-access PQ/hb latency overlaps the score/softmax VALU work.
__global__ __launch_bounds__(256)
void node_fused(const ushort* __restrict__ PQ, const ushort* __restrict__ hb_in,
                const int* __restrict__ esrc, const int* __restrict__ rowptr,
                const float* __restrict__ wf, const int* __restrict__ flag,
                ushort* __restrict__ hb_out, void* __restrict__ out, int write_out) {
  const int wave = threadIdx.x >> 6, lane = threadIdx.x & 63;
  const int d = blockIdx.x * 4 + wave;
  const int beg = rowptr[d], end = rowptr[d + 1];
  const int c0 = lane * 8;

  const uint4 qv = *(const uint4*)(PQ + (size_t)d * 1024 + 512 + c0);
  const uint qw[4] = {qv.x, qv.y, qv.z, qv.w};
  float q[8], w[8];
#pragma unroll
  for (int i = 0; i < 4; ++i) {
    q[2 * i]     = __uint_as_float(qw[i] << 16);
    q[2 * i + 1] = __uint_as_float(qw[i] & 0xffff0000u);
  }
  const float4 w0 = *(const float4*)(wf + c0);
  const float4 w1 = *(const float4*)(wf + c0 + 4);
  w[0] = w0.x; w[1] = w0.y; w[2] = w0.z; w[3] = w0.w;
  w[4] = w1.x; w[5] = w1.y; w[6] = w1.z; w[7] = w1.w;

  float m = -3e38f, den = 0.f;
  float acc[8] = {0.f, 0.f, 0.f, 0.f, 0.f, 0.f, 0.f, 0.f};

  if (beg < end) {
    const int last = end - 1;
    // prologue: fill pipeline (esrc[beg..] is contiguous -> index loads are cheap)
    const int s0 = esrc[beg];
    int sN = esrc[(beg + 1 <= last) ? beg + 1 : last];     // src for edge j+1
    uint4 pv0 = *(const uint4*)(PQ + (size_t)s0 * 1024 + c0);
    uint4 hv0 = *(const uint4*)(hb_in + (size_t)s0 * 512 + c0);

    for (int j = beg; j < end; ++j) {
      // issue next-edge loads first (depth-1 data prefetch, depth-2 index prefetch)
      const int s2 = esrc[(j + 2 <= last) ? j + 2 : last];
      uint4 pv1 = pv0, hv1 = hv0;
      if (j < last) {   // wave-uniform branch
        pv1 = *(const uint4*)(PQ + (size_t)sN * 1024 + c0);
        hv1 = *(const uint4*)(hb_in + (size_t)sN * 512 + c0);
      }

      // compute edge j from registers loaded last iteration
      const uint pw[4] = {pv0.x, pv0.y, pv0.z, pv0.w};
      const uint hw[4] = {hv0.x, hv0.y, hv0.z, hv0.w};
      float t = 0.f;
#pragma unroll
      for (int i = 0; i < 4; ++i) {
        float ea = __uint_as_float(pw[i] << 16) + q[2 * i];
        float eb = __uint_as_float(pw[i] & 0xffff0000u) + q[2 * i + 1];
        ea = (ea > 0.f) ? ea : 0.01f * ea;
        eb = (eb > 0.f) ? eb : 0.01f * eb;
        t += ea * w[2 * i] + eb * w[2 * i + 1];
      }
      t += __shfl_xor(t, 1);
      t += __shfl_xor(t, 2);
      t += __shfl_xor(t, 4);
      // online softmax; rescale path only when some head's max moves (wave-uniform)
      if (__any(t > m)) {
        const float mnew = fmaxf(m, t);
        const float corr = __expf(m - mnew);
        const float ex = __expf(t - mnew);
        den = den * corr + ex;
#pragma unroll
        for (int i = 0; i < 4; ++i) {
          acc[2 * i]     = acc[2 * i] * corr     + ex * __uint_as_float(hw[i] << 16);
          acc[2 * i + 1] = acc[2 * i + 1] * corr + ex * __uint_as_float(hw[i] & 0xffff0000u);
        }
        m = mnew;
      } else {
        const float ex = __expf(t - m);
        den += ex;
#pragma unroll
        for (int i = 0; i < 4; ++i) {
          acc[2 * i]     += ex * __uint_as_float(hw[i] << 16);
          acc[2 * i + 1] += ex * __uint_as_float(hw[i] & 0xffff0000u);
        }
      }
      // rotate pipeline
      pv0 = pv1; hv0 = hv1; sN = s2;
    }
  }

  const float inv = (end > beg) ? (1.f / den) : 0.f;
  uint o[4];
#pragma unroll
  for (int i = 0; i < 4; ++i) {
    float v0 = acc[2 * i] * inv, v1 = acc[2 * i + 1] * inv;
    o[i] = (uint)f2bf(v0) | ((uint)f2bf(v1) << 16);
  }
  u32x4 ov = {o[0], o[1], o[2], o[3]};
  *(u32x4*)(hb_out + (size_t)d * 512 + c0) = ov;
  if (write_out) {
    if (*flag) {
      __builtin_nontemporal_store(ov, (u32x4*)((ushort*)out + (size_t)d * 512 + c0));
    } else {
      f32x4 f0 = {acc[0] * inv, acc[1] * inv, acc[2] * inv, acc[3] * inv};
      f32x4 f1 = {acc[4] * inv, acc[5] * inv, acc[6] * inv, acc[7] * inv};
      __builtin_nontemporal_store(f0, (f32x4*)((float*)out + (size_t)d * 512 + c0));
      __builtin_nontemporal_store(f1, (f32x4*)((float*)out + (size_t)d * 512 + c0 + 4));
    }
  }
}

extern "C" void kernel_launch(void* const* d_in, const int* in_sizes, int n_in,
                              void* d_out, int out_size, void* d_ws, size_t ws_size,
                              hipStream_t stream) {
  const void* x   = d_in[0];
  const int*  src = (const int*)d_in[2];
  const int*  dst = (const int*)d_in[3];
  const void* Wn  = d_in[4];
  const void* bn  = d_in[5];
  const void* Wa  = d_in[8];
  const void* ba  = d_in[9];
  const void* aw  = d_in[10];

  char* ws = (char*)d_ws;
  size_t off = 0;
  auto alloc = [&](size_t bytes) {
    char* p = ws + off;
    off = (off + bytes + 255) & ~(size_t)255;
    return p;
  };
  ushort* hbA    = (ushort*)alloc((size_t)N_NODES * 512 * 2);   // 32 MB
  ushort* hbB    = (ushort*)alloc((size_t)N_NODES * 512 * 2);   // 32 MB
  ushort* PQ     = (ushort*)alloc((size_t)N_NODES * 1024 * 2);  // 64 MB
  int*    esrc   = (int*)   alloc((size_t)N_EDGES * 4);         // 1 MB
  int*    rowptr = (int*)   alloc((size_t)(N_NODES + 1) * 4);
  int*    cnt    = (int*)   alloc((size_t)N_NODES * 4);
  int*    cursor = (int*)   alloc((size_t)N_NODES * 4);
  ushort* W2T    = (ushort*)alloc((size_t)1024 * 512 * 2);      // 1 MB
  ushort* WcT    = (ushort*)alloc((size_t)1024 * 128 * 2);      // 256 KB
  ushort* Wn_pad = (ushort*)alloc((size_t)128 * 512 * 2);
  float*  bias2  = (float*) alloc(1024 * 4);
  float*  bc     = (float*) alloc(1024 * 4);
  float*  zbias  = (float*) alloc(128 * 4);
  ushort* xp     = (ushort*)alloc((size_t)N_NODES * 128 * 2);   // 8 MB
  ushort* WnpT   = (ushort*)alloc((size_t)512 * 128 * 2);
  float*  bnf    = (float*) alloc(512 * 4);
  float*  wf     = (float*) alloc(512 * 4);
  int*    flag   = (int*)   alloc(256);

  detect_dtype<<<1, 256, 0, stream>>>((const uint*)x, flag);
  prep_all<<<2564 + (N_NODES * 128) / 256, 256, 0, stream>>>(
      Wa, Wn, ba, bn, aw, x, flag, W2T, WnpT, Wn_pad, bias2, bnf, wf, zbias, xp);
  build_bc<<<256, 256, 0, stream>>>(W2T, bnf, bias2, bc);
  // WcT[1024][128] = W2T[1024][512] @ Wn_pad^T  (Wc = Wn_pad @ W2)
  {
    dim3 g(128 / 128, 1024 / 128);
    gemm_bf16<<<g, 256, 0, stream>>>(W2T, Wn_pad, zbias, WcT, 1024, 128, 512);
  }

  // CSR over dst
  hipMemsetAsync(cnt, 0, (size_t)N_NODES * 4, stream);
  csr_count<<<N_EDGES / 256, 256, 0, stream>>>(dst, cnt);
  csr_scan<<<1, 1024, 0, stream>>>(cnt, rowptr, cursor);
  csr_fill<<<N_EDGES / 256, 256, 0, stream>>>(dst, src, cursor, esrc);

  // h0 = xp @ Wnp + bn   (needed as aggregation input)
  {
    dim3 g(512 / 128, N_NODES / 128);
    gemm_bf16<<<g, 256, 0, stream>>>(xp, WnpT, bnf, hbA, N_NODES, 512, 128);
  }

  // layer 1: PQ = xp @ Wc + bc   (folded, K=128)
  {
    dim3 g(1024 / 128, N_NODES / 128);
    gemm_bf16<<<g, 256, 0, stream>>>(xp, WcT, bc, PQ, N_NODES, 1024, 128);
  }
  node_fused<<<N_NODES / 4, 256, 0, stream>>>(PQ, hbA, esrc, rowptr, wf, flag,
                                              hbB, d_out, 0);

  // layer 2: PQ = h1 @ W2 + bias2   (K=512)
  {
    dim3 g(1024 / 128, N_NODES / 128);
    gemm_bf16<<<g, 256, 0, stream>>>(hbB, W2T, bias2, PQ, N_NODES, 1024, 512);
  }
  node_fused<<<N_NODES / 4, 256, 0, stream>>>(PQ, hbB, esrc, rowptr, wf, flag,
                                              hbA, d_out, 1);
}